// Round 1
// baseline (196.540 us; speedup 1.0000x reference)
//
#include <hip/hip_runtime.h>

typedef unsigned int u32;
typedef unsigned short u16;
typedef float f32x4 __attribute__((ext_vector_type(4)));
typedef short bf16x8 __attribute__((ext_vector_type(8)));

__device__ __forceinline__ u16 f2bf(float f) {
  u32 u = __builtin_bit_cast(u32, f);
  u += 0x7FFFu + ((u >> 16) & 1u);
  return (u16)(u >> 16);
}
__device__ __forceinline__ float bf2f(u32 u) {
  return __builtin_bit_cast(float, u << 16);
}
__device__ __forceinline__ void gload_lds16(const void* g, void* l) {
  __builtin_amdgcn_global_load_lds(
      (const __attribute__((address_space(1))) void*)g,
      (__attribute__((address_space(3))) void*)l, 16, 0, 0);
}

// ---- cast f32 -> bf16, 4 at a time ----
__global__ __launch_bounds__(256) void cast_f32_bf16_k(
    const float4* __restrict__ in, uint2* __restrict__ out, int n4) {
  int i = blockIdx.x * 256 + threadIdx.x;
  if (i < n4) {
    float4 v = in[i];
    uint2 o;
    o.x = (u32)f2bf(v.x) | ((u32)f2bf(v.y) << 16);
    o.y = (u32)f2bf(v.z) | ((u32)f2bf(v.w) << 16);
    out[i] = o;
  }
}

// ---- transpose + cast: f32 [R][C] -> bf16 [C][R] ----
__global__ __launch_bounds__(256) void transpose_cast_k(
    const float* __restrict__ in, u16* __restrict__ out, int R, int C) {
  __shared__ float tile[32][33];
  int c0 = blockIdx.x * 32, r0 = blockIdx.y * 32;
  int tx = threadIdx.x, ty = threadIdx.y;  // (32,8)
  #pragma unroll
  for (int j = 0; j < 4; j++) {
    int r = r0 + ty + j * 8, c = c0 + tx;
    if (r < R && c < C) tile[ty + j * 8][tx] = in[(size_t)r * C + c];
  }
  __syncthreads();
  #pragma unroll
  for (int j = 0; j < 4; j++) {
    int c = c0 + ty + j * 8, r = r0 + tx;
    if (r < R && c < C) out[(size_t)c * R + r] = f2bf(tile[tx][ty + j * 8]);
  }
}

// ---- bf16 MFMA GEMM: C = act(A[M,K] @ Bt[N,K]^T + bias), bf16 out ----
// 128x128 tile, BK=64, 4 waves (2x2), 16x16x32 MFMA, global_load_lds w/
// XOR-swizzled source (byte ^= (row&7)<<4) + swizzled ds_read_b128.
__global__ __launch_bounds__(256) void gemm_bt_k(
    const u16* __restrict__ A, const u16* __restrict__ Bt,
    const float* __restrict__ bias, u16* __restrict__ C,
    int M, int N, int K, int relu) {
  __shared__ __align__(16) char lds[32768];
  char* ldsA = lds;
  char* ldsB = lds + 16384;
  const int tid = threadIdx.x;
  const int bn = blockIdx.x, bm = blockIdx.y;
  const int wave = tid >> 6, lane = tid & 63;
  const int wm = wave >> 1, wn = wave & 1;
  const int l15 = lane & 15, l4 = lane >> 4;

  f32x4 acc[4][4];
  #pragma unroll
  for (int m = 0; m < 4; m++)
    #pragma unroll
    for (int n = 0; n < 4; n++) acc[m][n] = (f32x4){0.f, 0.f, 0.f, 0.f};

  int srow[4], scol[4];
  #pragma unroll
  for (int t = 0; t < 4; t++) {
    int chunk = tid + t * 256;
    srow[t] = chunk >> 3;
    scol[t] = ((chunk & 7) ^ (srow[t] & 7)) * 8;  // element offset (x8 bf16)
  }

  for (int kt = 0; kt < K; kt += 64) {
    #pragma unroll
    for (int t = 0; t < 4; t++) {
      int chunk = tid + t * 256;
      gload_lds16(A + (size_t)(bm * 128 + srow[t]) * K + kt + scol[t],
                  ldsA + chunk * 16);
      gload_lds16(Bt + (size_t)(bn * 128 + srow[t]) * K + kt + scol[t],
                  ldsB + chunk * 16);
    }
    asm volatile("s_waitcnt vmcnt(0)" ::: "memory");
    __syncthreads();
    #pragma unroll
    for (int kk = 0; kk < 2; kk++) {
      bf16x8 af[4], bfr[4];
      #pragma unroll
      for (int m = 0; m < 4; m++) {
        int r = wm * 64 + m * 16 + l15;
        int kb = kk * 64 + l4 * 16;
        af[m] = *(const bf16x8*)(ldsA + r * 128 + (kb ^ ((r & 7) << 4)));
      }
      #pragma unroll
      for (int n = 0; n < 4; n++) {
        int r = wn * 64 + n * 16 + l15;
        int kb = kk * 64 + l4 * 16;
        bfr[n] = *(const bf16x8*)(ldsB + r * 128 + (kb ^ ((r & 7) << 4)));
      }
      #pragma unroll
      for (int m = 0; m < 4; m++)
        #pragma unroll
        for (int n = 0; n < 4; n++)
          acc[m][n] = __builtin_amdgcn_mfma_f32_16x16x32_bf16(
              af[m], bfr[n], acc[m][n], 0, 0, 0);
    }
    __syncthreads();
  }

  #pragma unroll
  for (int n = 0; n < 4; n++) {
    int col = bn * 128 + wn * 64 + n * 16 + l15;
    float bv = bias[col];
    #pragma unroll
    for (int m = 0; m < 4; m++) {
      int row0 = bm * 128 + wm * 64 + m * 16 + l4 * 4;
      #pragma unroll
      for (int r = 0; r < 4; r++) {
        float v = acc[m][n][r] + bv;
        if (relu) v = v > 0.f ? v : 0.f;
        C[(size_t)(row0 + r) * N + col] = f2bf(v);
      }
    }
  }
}

__device__ __forceinline__ float dot8(uint4 a, uint4 b) {
  float s = 0.f;
  s += bf2f(a.x & 0xFFFFu) * bf2f(b.x & 0xFFFFu);
  s += bf2f(a.x >> 16) * bf2f(b.x >> 16);
  s += bf2f(a.y & 0xFFFFu) * bf2f(b.y & 0xFFFFu);
  s += bf2f(a.y >> 16) * bf2f(b.y >> 16);
  s += bf2f(a.z & 0xFFFFu) * bf2f(b.z & 0xFFFFu);
  s += bf2f(a.z >> 16) * bf2f(b.z >> 16);
  s += bf2f(a.w & 0xFFFFu) * bf2f(b.w & 0xFFFFu);
  s += bf2f(a.w >> 16) * bf2f(b.w >> 16);
  return s;
}

// ---- skinny GEMM3: o[m,c] = h2[m,:] . w3t[c,:] + b3[c]; out transposed
// ot[(b*16+c)*2048 + s] for the scan. lane = c*4+g, g splits K.
__global__ __launch_bounds__(256) void gemm3_k(
    const u16* __restrict__ h2, const u16* __restrict__ w3t,
    const float* __restrict__ b3, float* __restrict__ ot, int Mtot) {
  int wave = threadIdx.x >> 6, lane = threadIdx.x & 63;
  int c = lane >> 2, g = lane & 3;
  for (int m = blockIdx.x * 4 + wave; m < Mtot; m += gridDim.x * 4) {
    const u16* hrow = h2 + (size_t)m * 1024;
    const u16* wrow = w3t + (size_t)c * 1024;
    float acc = 0.f;
    #pragma unroll 4
    for (int it = 0; it < 32; it++) {
      int k0 = (it * 4 + g) * 8;
      uint4 hv = *(const uint4*)(hrow + k0);
      uint4 wv = *(const uint4*)(wrow + k0);
      acc += dot8(hv, wv);
    }
    acc += __shfl_xor(acc, 1, 64);
    acc += __shfl_xor(acc, 2, 64);
    if (g == 0) {
      int b = m >> 11, s = m & 2047;
      ot[((size_t)(b * 16 + c)) * 2048 + s] = acc + b3[c];
    }
  }
}

// ---- decay recurrence + cumsum: one thread per (b,c) chain ----
__global__ __launch_bounds__(128) void scan_k(
    const float* __restrict__ ot, float* __restrict__ out) {
  int t = threadIdx.x;  // 0..127 == b*16+c
  int b = t >> 4, c = t & 15;
  float dinv = __builtin_bit_cast(float, (u32)((127 - (c + 3)) << 23));  // 2^-(c+3)
  float d = 1.f - dinv;
  const float4* src = (const float4*)(ot + (size_t)t * 2048);
  float* dst = out + (size_t)b * 32768 + c;
  float m = 0.f, a = 0.f;
  for (int i = 0; i < 512; i++) {
    float4 v = src[i];
    m = d * m + v.x; a += m; dst[(i * 4 + 0) * 16] = a;
    m = d * m + v.y; a += m; dst[(i * 4 + 1) * 16] = a;
    m = d * m + v.z; a += m; dst[(i * 4 + 2) * 16] = a;
    m = d * m + v.w; a += m; dst[(i * 4 + 3) * 16] = a;
  }
}

extern "C" void kernel_launch(void* const* d_in, const int* in_sizes, int n_in,
                              void* d_out, int out_size, void* d_ws, size_t ws_size,
                              hipStream_t stream) {
  const float* x  = (const float*)d_in[0];
  const float* w1 = (const float*)d_in[1];
  const float* b1 = (const float*)d_in[2];
  const float* w2 = (const float*)d_in[3];
  const float* b2 = (const float*)d_in[4];
  const float* w3 = (const float*)d_in[5];
  const float* b3 = (const float*)d_in[6];
  // d_in[7] (D) intentionally unused: decay recurrence replaces the einsum.
  float* out = (float*)d_out;

  char* ws = (char*)d_ws;
  size_t off = 0;
  u16* A1  = (u16*)(ws + off); off += (size_t)16384 * 512 * 2;   // x bf16
  u16* h1  = (u16*)(ws + off); off += (size_t)16384 * 1024 * 2;  // layer1 out
  u16* h2  = (u16*)(ws + off); off += (size_t)16384 * 1024 * 2;  // layer2 out
  u16* w1t = (u16*)(ws + off); off += (size_t)1024 * 512 * 2;
  u16* w2t = (u16*)(ws + off); off += (size_t)1024 * 1024 * 2;
  u16* w3t = (u16*)(ws + off); off += (size_t)16 * 1024 * 2;
  float* ot = (float*)(ws + off); off += (size_t)128 * 2048 * 4; // [b*16+c][t]

  cast_f32_bf16_k<<<8192, 256, 0, stream>>>((const float4*)x, (uint2*)A1,
                                            16384 * 512 / 4);
  dim3 tb(32, 8);
  transpose_cast_k<<<dim3(32, 16), tb, 0, stream>>>(w1, w1t, 512, 1024);
  transpose_cast_k<<<dim3(32, 32), tb, 0, stream>>>(w2, w2t, 1024, 1024);
  transpose_cast_k<<<dim3(1, 32),  tb, 0, stream>>>(w3, w3t, 1024, 16);

  gemm_bt_k<<<dim3(8, 128), 256, 0, stream>>>(A1, w1t, b1, h1,
                                              16384, 1024, 512, 1);
  gemm_bt_k<<<dim3(8, 128), 256, 0, stream>>>(h1, w2t, b2, h2,
                                              16384, 1024, 1024, 1);
  gemm3_k<<<2048, 256, 0, stream>>>(h2, w3t, b3, ot, 16384);
  scan_k<<<1, 128, 0, stream>>>(ot, out);
}

// Round 2
// 191.031 us; speedup vs baseline: 1.0288x; 1.0288x over previous
//
#include <hip/hip_runtime.h>

typedef unsigned int u32;
typedef unsigned short u16;
typedef float f32x4 __attribute__((ext_vector_type(4)));
typedef short bf16x8 __attribute__((ext_vector_type(8)));

__device__ __forceinline__ u16 f2bf(float f) {
  u32 u = __builtin_bit_cast(u32, f);
  u += 0x7FFFu + ((u >> 16) & 1u);
  return (u16)(u >> 16);
}
__device__ __forceinline__ float bf2f(u32 u) {
  return __builtin_bit_cast(float, u << 16);
}
__device__ __forceinline__ void gload_lds16(const void* g, void* l) {
  __builtin_amdgcn_global_load_lds(
      (const __attribute__((address_space(1))) void*)g,
      (__attribute__((address_space(3))) void*)l, 16, 0, 0);
}

// ---- cast f32 -> bf16, 4 at a time ----
__global__ __launch_bounds__(256) void cast_f32_bf16_k(
    const float4* __restrict__ in, uint2* __restrict__ out, int n4) {
  int i = blockIdx.x * 256 + threadIdx.x;
  if (i < n4) {
    float4 v = in[i];
    uint2 o;
    o.x = (u32)f2bf(v.x) | ((u32)f2bf(v.y) << 16);
    o.y = (u32)f2bf(v.z) | ((u32)f2bf(v.w) << 16);
    out[i] = o;
  }
}

// ---- transpose + cast: f32 [R][C] -> bf16 [C][R] ----
__global__ __launch_bounds__(256) void transpose_cast_k(
    const float* __restrict__ in, u16* __restrict__ out, int R, int C) {
  __shared__ float tile[32][33];
  int c0 = blockIdx.x * 32, r0 = blockIdx.y * 32;
  int tx = threadIdx.x, ty = threadIdx.y;  // (32,8)
  #pragma unroll
  for (int j = 0; j < 4; j++) {
    int r = r0 + ty + j * 8, c = c0 + tx;
    if (r < R && c < C) tile[ty + j * 8][tx] = in[(size_t)r * C + c];
  }
  __syncthreads();
  #pragma unroll
  for (int j = 0; j < 4; j++) {
    int c = c0 + ty + j * 8, r = r0 + tx;
    if (r < R && c < C) out[(size_t)c * R + r] = f2bf(tile[tx][ty + j * 8]);
  }
}

// ---- bf16 MFMA GEMM: C = act(A[M,K] @ Bt[N,K]^T + bias), bf16 out ----
// BM=256, BN=128, BK=64. 512 threads = 8 waves (4M x 2N), per-wave 64x64.
// 3-slot LDS ring (144 KiB): stage tile t+2 while computing tile t ->
// counted vmcnt(6) gate (T4), never a full drain in the main loop.
// Two MFMA phases per K-tile with s_barrier + lgkmcnt + setprio (T3+T5).
// LDS XOR involution on both sides (rule #21): src col8 ^= row&7, read ditto.
__global__ __launch_bounds__(512, 2) void gemm_bt_k(
    const u16* __restrict__ A, const u16* __restrict__ Bt,
    const float* __restrict__ bias, u16* __restrict__ C,
    int M, int N, int K, int relu) {
  __shared__ __align__(16) char lds[3 * 49152];  // slot: A 32K + B 16K
  const int tid = threadIdx.x;
  const int bn = blockIdx.x, bm = blockIdx.y;
  const int wave = tid >> 6, lane = tid & 63;
  const int wm = wave >> 1, wn = wave & 1;  // 4 x 2 wave grid
  const int l15 = lane & 15, l4 = lane >> 4;
  const int NT = K >> 6;
  const size_t arow0 = (size_t)bm * 256, brow0 = (size_t)bn * 128;

  f32x4 acc[4][4];
  #pragma unroll
  for (int m = 0; m < 4; m++)
    #pragma unroll
    for (int n = 0; n < 4; n++) acc[m][n] = (f32x4){0.f, 0.f, 0.f, 0.f};

  // stage K-tile kt into slot s (linear LDS dest, inverse-swizzled source)
  auto stage = [&](int kt, int s) {
    char* sA = lds + s * 49152;
    char* sB = sA + 32768;
    #pragma unroll
    for (int j = 0; j < 4; j++) {
      int ch = tid + j * 512;            // 2048 chunks = 256 rows x 8
      int row = ch >> 3;
      int col8 = (ch & 7) ^ (row & 7);
      gload_lds16(A + (arow0 + row) * K + kt * 64 + col8 * 8, sA + ch * 16);
    }
    #pragma unroll
    for (int j = 0; j < 2; j++) {
      int ch = tid + j * 512;            // 1024 chunks = 128 rows x 8
      int row = ch >> 3;
      int col8 = (ch & 7) ^ (row & 7);
      gload_lds16(Bt + (brow0 + row) * K + kt * 64 + col8 * 8, sB + ch * 16);
    }
  };

  // prologue: tiles 0,1 in flight; wait tile 0 only (vmcnt 6 = tile 1 stays)
  stage(0, 0);
  stage(1, 1);
  asm volatile("s_waitcnt vmcnt(6)" ::: "memory");
  __builtin_amdgcn_s_barrier();

  for (int t = 0; t < NT; t++) {
    const int s = t % 3;
    const char* sA = lds + s * 49152;
    const char* sB = sA + 32768;

    // ---- phase 0: read all B frags + A m={0,1}; issue stage(t+2) ----
    bf16x8 bf[2][4];  // [ks][n]
    #pragma unroll
    for (int ks = 0; ks < 2; ks++)
      #pragma unroll
      for (int n = 0; n < 4; n++) {
        int r = wn * 64 + n * 16 + l15;
        bf[ks][n] = *(const bf16x8*)(sB + r * 128 +
                                     (((ks * 4 + l4) ^ (r & 7)) << 4));
      }
    bf16x8 af0[2][2];  // [m][ks]
    #pragma unroll
    for (int m = 0; m < 2; m++)
      #pragma unroll
      for (int ks = 0; ks < 2; ks++) {
        int r = wm * 64 + m * 16 + l15;
        af0[m][ks] = *(const bf16x8*)(sA + r * 128 +
                                      (((ks * 4 + l4) ^ (r & 7)) << 4));
      }
    if (t + 2 < NT) stage(t + 2, (t + 2) % 3);

    __builtin_amdgcn_s_barrier();
    asm volatile("s_waitcnt lgkmcnt(0)" ::: "memory");
    __builtin_amdgcn_sched_barrier(0);
    __builtin_amdgcn_s_setprio(1);
    #pragma unroll
    for (int m = 0; m < 2; m++)
      #pragma unroll
      for (int n = 0; n < 4; n++)
        #pragma unroll
        for (int ks = 0; ks < 2; ks++)
          acc[m][n] = __builtin_amdgcn_mfma_f32_16x16x32_bf16(
              af0[m][ks], bf[ks][n], acc[m][n], 0, 0, 0);
    __builtin_amdgcn_s_setprio(0);

    // ---- phase 1: read A m={2,3}, then barrier-aligned MFMA cluster ----
    bf16x8 af1[2][2];
    #pragma unroll
    for (int m = 0; m < 2; m++)
      #pragma unroll
      for (int ks = 0; ks < 2; ks++) {
        int r = wm * 64 + (m + 2) * 16 + l15;
        af1[m][ks] = *(const bf16x8*)(sA + r * 128 +
                                      (((ks * 4 + l4) ^ (r & 7)) << 4));
      }
    __builtin_amdgcn_s_barrier();
    asm volatile("s_waitcnt lgkmcnt(0)" ::: "memory");
    __builtin_amdgcn_sched_barrier(0);
    __builtin_amdgcn_s_setprio(1);
    #pragma unroll
    for (int m = 0; m < 2; m++)
      #pragma unroll
      for (int n = 0; n < 4; n++)
        #pragma unroll
        for (int ks = 0; ks < 2; ks++)
          acc[m + 2][n] = __builtin_amdgcn_mfma_f32_16x16x32_bf16(
              af1[m][ks], bf[ks][n], acc[m + 2][n], 0, 0, 0);
    __builtin_amdgcn_s_setprio(0);

    // ---- iter-end gate: tile t+1 landed; tile t+2 stays in flight ----
    if (t + 1 < NT) {
      if (t + 2 < NT)
        asm volatile("s_waitcnt vmcnt(6)" ::: "memory");
      else
        asm volatile("s_waitcnt vmcnt(0)" ::: "memory");
      __builtin_amdgcn_s_barrier();
    }
  }

  #pragma unroll
  for (int n = 0; n < 4; n++) {
    int col = bn * 128 + wn * 64 + n * 16 + l15;
    float bv = bias[col];
    #pragma unroll
    for (int m = 0; m < 4; m++) {
      int row0 = bm * 256 + wm * 64 + m * 16 + l4 * 4;
      #pragma unroll
      for (int r = 0; r < 4; r++) {
        float v = acc[m][n][r] + bv;
        if (relu) v = v > 0.f ? v : 0.f;
        C[(size_t)(row0 + r) * N + col] = f2bf(v);
      }
    }
  }
}

__device__ __forceinline__ float dot8(uint4 a, uint4 b) {
  float s = 0.f;
  s += bf2f(a.x & 0xFFFFu) * bf2f(b.x & 0xFFFFu);
  s += bf2f(a.x >> 16) * bf2f(b.x >> 16);
  s += bf2f(a.y & 0xFFFFu) * bf2f(b.y & 0xFFFFu);
  s += bf2f(a.y >> 16) * bf2f(b.y >> 16);
  s += bf2f(a.z & 0xFFFFu) * bf2f(b.z & 0xFFFFu);
  s += bf2f(a.z >> 16) * bf2f(b.z >> 16);
  s += bf2f(a.w & 0xFFFFu) * bf2f(b.w & 0xFFFFu);
  s += bf2f(a.w >> 16) * bf2f(b.w >> 16);
  return s;
}

// ---- skinny GEMM3: o[m,c] = h2[m,:] . w3t[c,:] + b3[c]; out transposed
// ot[(b*16+c)*2048 + s] for the scan. lane = c*4+g, g splits K.
__global__ __launch_bounds__(256) void gemm3_k(
    const u16* __restrict__ h2, const u16* __restrict__ w3t,
    const float* __restrict__ b3, float* __restrict__ ot, int Mtot) {
  int wave = threadIdx.x >> 6, lane = threadIdx.x & 63;
  int c = lane >> 2, g = lane & 3;
  for (int m = blockIdx.x * 4 + wave; m < Mtot; m += gridDim.x * 4) {
    const u16* hrow = h2 + (size_t)m * 1024;
    const u16* wrow = w3t + (size_t)c * 1024;
    float acc = 0.f;
    #pragma unroll 4
    for (int it = 0; it < 32; it++) {
      int k0 = (it * 4 + g) * 8;
      uint4 hv = *(const uint4*)(hrow + k0);
      uint4 wv = *(const uint4*)(wrow + k0);
      acc += dot8(hv, wv);
    }
    acc += __shfl_xor(acc, 1, 64);
    acc += __shfl_xor(acc, 2, 64);
    if (g == 0) {
      int b = m >> 11, s = m & 2047;
      ot[((size_t)(b * 16 + c)) * 2048 + s] = acc + b3[c];
    }
  }
}

// ---- decay recurrence + cumsum: one thread per (b,c) chain ----
__global__ __launch_bounds__(128) void scan_k(
    const float* __restrict__ ot, float* __restrict__ out) {
  int t = threadIdx.x;  // 0..127 == b*16+c
  int b = t >> 4, c = t & 15;
  float dinv = __builtin_bit_cast(float, (u32)((127 - (c + 3)) << 23));  // 2^-(c+3)
  float d = 1.f - dinv;
  const float4* src = (const float4*)(ot + (size_t)t * 2048);
  float* dst = out + (size_t)b * 32768 + c;
  float m = 0.f, a = 0.f;
  for (int i = 0; i < 512; i++) {
    float4 v = src[i];
    m = d * m + v.x; a += m; dst[(i * 4 + 0) * 16] = a;
    m = d * m + v.y; a += m; dst[(i * 4 + 1) * 16] = a;
    m = d * m + v.z; a += m; dst[(i * 4 + 2) * 16] = a;
    m = d * m + v.w; a += m; dst[(i * 4 + 3) * 16] = a;
  }
}

extern "C" void kernel_launch(void* const* d_in, const int* in_sizes, int n_in,
                              void* d_out, int out_size, void* d_ws, size_t ws_size,
                              hipStream_t stream) {
  const float* x  = (const float*)d_in[0];
  const float* w1 = (const float*)d_in[1];
  const float* b1 = (const float*)d_in[2];
  const float* w2 = (const float*)d_in[3];
  const float* b2 = (const float*)d_in[4];
  const float* w3 = (const float*)d_in[5];
  const float* b3 = (const float*)d_in[6];
  // d_in[7] (D) intentionally unused: decay recurrence replaces the einsum.
  float* out = (float*)d_out;

  char* ws = (char*)d_ws;
  size_t off = 0;
  u16* A1  = (u16*)(ws + off); off += (size_t)16384 * 512 * 2;   // x bf16
  u16* h1  = (u16*)(ws + off); off += (size_t)16384 * 1024 * 2;  // layer1 out
  u16* h2  = (u16*)(ws + off); off += (size_t)16384 * 1024 * 2;  // layer2 out
  u16* w1t = (u16*)(ws + off); off += (size_t)1024 * 512 * 2;
  u16* w2t = (u16*)(ws + off); off += (size_t)1024 * 1024 * 2;
  u16* w3t = (u16*)(ws + off); off += (size_t)16 * 1024 * 2;
  float* ot = (float*)(ws + off); off += (size_t)128 * 2048 * 4; // [b*16+c][t]

  cast_f32_bf16_k<<<8192, 256, 0, stream>>>((const float4*)x, (uint2*)A1,
                                            16384 * 512 / 4);
  dim3 tb(32, 8);
  transpose_cast_k<<<dim3(32, 16), tb, 0, stream>>>(w1, w1t, 512, 1024);
  transpose_cast_k<<<dim3(32, 32), tb, 0, stream>>>(w2, w2t, 1024, 1024);
  transpose_cast_k<<<dim3(1, 32),  tb, 0, stream>>>(w3, w3t, 1024, 16);

  gemm_bt_k<<<dim3(8, 64), 512, 0, stream>>>(A1, w1t, b1, h1,
                                             16384, 1024, 512, 1);
  gemm_bt_k<<<dim3(8, 64), 512, 0, stream>>>(h1, w2t, b2, h2,
                                             16384, 1024, 1024, 1);
  gemm3_k<<<2048, 256, 0, stream>>>(h2, w3t, b3, ot, 16384);
  scan_k<<<1, 128, 0, stream>>>(ot, out);
}

// Round 3
// 128.024 us; speedup vs baseline: 1.5352x; 1.4922x over previous
//
#include <hip/hip_runtime.h>

typedef unsigned int u32;
typedef unsigned short u16;
typedef float f32x4 __attribute__((ext_vector_type(4)));
typedef short bf16x8 __attribute__((ext_vector_type(8)));

__device__ __forceinline__ u16 f2bf(float f) {
  u32 u = __builtin_bit_cast(u32, f);
  u += 0x7FFFu + ((u >> 16) & 1u);
  return (u16)(u >> 16);
}
__device__ __forceinline__ float bf2f(u32 u) {
  return __builtin_bit_cast(float, u << 16);
}
__device__ __forceinline__ void gload_lds16(const void* g, void* l) {
  __builtin_amdgcn_global_load_lds(
      (const __attribute__((address_space(1))) void*)g,
      (__attribute__((address_space(3))) void*)l, 16, 0, 0);
}

// ---- cast f32 -> bf16, 4 at a time ----
__global__ __launch_bounds__(256) void cast_f32_bf16_k(
    const float4* __restrict__ in, uint2* __restrict__ out, int n4) {
  int i = blockIdx.x * 256 + threadIdx.x;
  if (i < n4) {
    float4 v = in[i];
    uint2 o;
    o.x = (u32)f2bf(v.x) | ((u32)f2bf(v.y) << 16);
    o.y = (u32)f2bf(v.z) | ((u32)f2bf(v.w) << 16);
    out[i] = o;
  }
}

// ---- transpose + cast: f32 [R][C] -> bf16 [C][R] ----
__global__ __launch_bounds__(256) void transpose_cast_k(
    const float* __restrict__ in, u16* __restrict__ out, int R, int C) {
  __shared__ float tile[32][33];
  int c0 = blockIdx.x * 32, r0 = blockIdx.y * 32;
  int tx = threadIdx.x, ty = threadIdx.y;  // (32,8)
  #pragma unroll
  for (int j = 0; j < 4; j++) {
    int r = r0 + ty + j * 8, c = c0 + tx;
    if (r < R && c < C) tile[ty + j * 8][tx] = in[(size_t)r * C + c];
  }
  __syncthreads();
  #pragma unroll
  for (int j = 0; j < 4; j++) {
    int c = c0 + ty + j * 8, r = r0 + tx;
    if (r < R && c < C) out[(size_t)c * R + r] = f2bf(tile[tx][ty + j * 8]);
  }
}

// ---- bf16 MFMA GEMM: C = act(A[M,K] @ Bt[N,K]^T + bias), bf16 out ----
// BM=256, BN=128, BK=64. 512 threads = 8 waves (4M x 2N), per-wave 64x64.
// 3-slot LDS ring (144 KiB), counted vmcnt(6) gate, 2 MFMA phases/K-tile.
// 1D grid of 512 with XCD-ownership mapping: xcd = rr&7 owns bm rows
// [xcd*8, xcd*8+8) for ALL bn -> each A-tile fetched into exactly one
// XCD's L2 (8x less A HBM traffic than the default round-robin).
__global__ __launch_bounds__(512, 2) void gemm_bt_k(
    const u16* __restrict__ A, const u16* __restrict__ Bt,
    const float* __restrict__ bias, u16* __restrict__ C,
    int M, int N, int K, int relu) {
  __shared__ __align__(16) char lds[3 * 49152];  // slot: A 32K + B 16K
  const int tid = threadIdx.x;
  const int rr = blockIdx.x;          // 512 blocks
  const int xcd = rr & 7, slot_id = rr >> 3;   // slot_id 0..63
  const int bm = (xcd << 3) | (slot_id >> 3);  // 0..63
  const int bn = slot_id & 7;                  // 0..7
  const int wave = tid >> 6, lane = tid & 63;
  const int wm = wave >> 1, wn = wave & 1;  // 4 x 2 wave grid
  const int l15 = lane & 15, l4 = lane >> 4;
  const int NT = K >> 6;
  const size_t arow0 = (size_t)bm * 256, brow0 = (size_t)bn * 128;

  f32x4 acc[4][4];
  #pragma unroll
  for (int m = 0; m < 4; m++)
    #pragma unroll
    for (int n = 0; n < 4; n++) acc[m][n] = (f32x4){0.f, 0.f, 0.f, 0.f};

  // stage K-tile kt into slot s (linear LDS dest, inverse-swizzled source)
  auto stage = [&](int kt, int s) {
    char* sA = lds + s * 49152;
    char* sB = sA + 32768;
    #pragma unroll
    for (int j = 0; j < 4; j++) {
      int ch = tid + j * 512;            // 2048 chunks = 256 rows x 8
      int row = ch >> 3;
      int col8 = (ch & 7) ^ (row & 7);
      gload_lds16(A + (arow0 + row) * K + kt * 64 + col8 * 8, sA + ch * 16);
    }
    #pragma unroll
    for (int j = 0; j < 2; j++) {
      int ch = tid + j * 512;            // 1024 chunks = 128 rows x 8
      int row = ch >> 3;
      int col8 = (ch & 7) ^ (row & 7);
      gload_lds16(Bt + (brow0 + row) * K + kt * 64 + col8 * 8, sB + ch * 16);
    }
  };

  // prologue: tiles 0,1 in flight; wait tile 0 only (vmcnt 6 = tile 1 stays)
  stage(0, 0);
  stage(1, 1);
  asm volatile("s_waitcnt vmcnt(6)" ::: "memory");
  __builtin_amdgcn_s_barrier();

  for (int t = 0; t < NT; t++) {
    const int s = t % 3;
    const char* sA = lds + s * 49152;
    const char* sB = sA + 32768;

    // ---- phase 0: read all B frags + A m={0,1}; issue stage(t+2) ----
    bf16x8 bf[2][4];  // [ks][n]
    #pragma unroll
    for (int ks = 0; ks < 2; ks++)
      #pragma unroll
      for (int n = 0; n < 4; n++) {
        int r = wn * 64 + n * 16 + l15;
        bf[ks][n] = *(const bf16x8*)(sB + r * 128 +
                                     (((ks * 4 + l4) ^ (r & 7)) << 4));
      }
    bf16x8 af0[2][2];  // [m][ks]
    #pragma unroll
    for (int m = 0; m < 2; m++)
      #pragma unroll
      for (int ks = 0; ks < 2; ks++) {
        int r = wm * 64 + m * 16 + l15;
        af0[m][ks] = *(const bf16x8*)(sA + r * 128 +
                                      (((ks * 4 + l4) ^ (r & 7)) << 4));
      }
    if (t + 2 < NT) stage(t + 2, (t + 2) % 3);

    __builtin_amdgcn_s_barrier();
    asm volatile("s_waitcnt lgkmcnt(0)" ::: "memory");
    __builtin_amdgcn_sched_barrier(0);
    __builtin_amdgcn_s_setprio(1);
    #pragma unroll
    for (int m = 0; m < 2; m++)
      #pragma unroll
      for (int n = 0; n < 4; n++)
        #pragma unroll
        for (int ks = 0; ks < 2; ks++)
          acc[m][n] = __builtin_amdgcn_mfma_f32_16x16x32_bf16(
              af0[m][ks], bf[ks][n], acc[m][n], 0, 0, 0);
    __builtin_amdgcn_s_setprio(0);

    // ---- phase 1: read A m={2,3}, then barrier-aligned MFMA cluster ----
    bf16x8 af1[2][2];
    #pragma unroll
    for (int m = 0; m < 2; m++)
      #pragma unroll
      for (int ks = 0; ks < 2; ks++) {
        int r = wm * 64 + (m + 2) * 16 + l15;
        af1[m][ks] = *(const bf16x8*)(sA + r * 128 +
                                      (((ks * 4 + l4) ^ (r & 7)) << 4));
      }
    __builtin_amdgcn_s_barrier();
    asm volatile("s_waitcnt lgkmcnt(0)" ::: "memory");
    __builtin_amdgcn_sched_barrier(0);
    __builtin_amdgcn_s_setprio(1);
    #pragma unroll
    for (int m = 0; m < 2; m++)
      #pragma unroll
      for (int n = 0; n < 4; n++)
        #pragma unroll
        for (int ks = 0; ks < 2; ks++)
          acc[m + 2][n] = __builtin_amdgcn_mfma_f32_16x16x32_bf16(
              af1[m][ks], bf[ks][n], acc[m + 2][n], 0, 0, 0);
    __builtin_amdgcn_s_setprio(0);

    // ---- iter-end gate: tile t+1 landed; tile t+2 stays in flight ----
    if (t + 1 < NT) {
      if (t + 2 < NT)
        asm volatile("s_waitcnt vmcnt(6)" ::: "memory");
      else
        asm volatile("s_waitcnt vmcnt(0)" ::: "memory");
      __builtin_amdgcn_s_barrier();
    }
  }

  #pragma unroll
  for (int n = 0; n < 4; n++) {
    int col = bn * 128 + wn * 64 + n * 16 + l15;
    float bv = bias[col];
    #pragma unroll
    for (int m = 0; m < 4; m++) {
      int row0 = bm * 256 + wm * 64 + m * 16 + l4 * 4;
      #pragma unroll
      for (int r = 0; r < 4; r++) {
        float v = acc[m][n][r] + bv;
        if (relu) v = v > 0.f ? v : 0.f;
        C[(size_t)(row0 + r) * N + col] = f2bf(v);
      }
    }
  }
}

__device__ __forceinline__ float dot8(uint4 a, uint4 b) {
  float s = 0.f;
  s += bf2f(a.x & 0xFFFFu) * bf2f(b.x & 0xFFFFu);
  s += bf2f(a.x >> 16) * bf2f(b.x >> 16);
  s += bf2f(a.y & 0xFFFFu) * bf2f(b.y & 0xFFFFu);
  s += bf2f(a.y >> 16) * bf2f(b.y >> 16);
  s += bf2f(a.z & 0xFFFFu) * bf2f(b.z & 0xFFFFu);
  s += bf2f(a.z >> 16) * bf2f(b.z >> 16);
  s += bf2f(a.w & 0xFFFFu) * bf2f(b.w & 0xFFFFu);
  s += bf2f(a.w >> 16) * bf2f(b.w >> 16);
  return s;
}

// ---- skinny GEMM3: o[m,c] = h2[m,:] . w3t[c,:] + b3[c]; out transposed
// ot[(b*16+c)*2048 + s] for the scan. lane = c*4+g, g splits K.
__global__ __launch_bounds__(256) void gemm3_k(
    const u16* __restrict__ h2, const u16* __restrict__ w3t,
    const float* __restrict__ b3, float* __restrict__ ot, int Mtot) {
  int wave = threadIdx.x >> 6, lane = threadIdx.x & 63;
  int c = lane >> 2, g = lane & 3;
  for (int m = blockIdx.x * 4 + wave; m < Mtot; m += gridDim.x * 4) {
    const u16* hrow = h2 + (size_t)m * 1024;
    const u16* wrow = w3t + (size_t)c * 1024;
    float acc = 0.f;
    #pragma unroll 4
    for (int it = 0; it < 32; it++) {
      int k0 = (it * 4 + g) * 8;
      uint4 hv = *(const uint4*)(hrow + k0);
      uint4 wv = *(const uint4*)(wrow + k0);
      acc += dot8(hv, wv);
    }
    acc += __shfl_xor(acc, 1, 64);
    acc += __shfl_xor(acc, 2, 64);
    if (g == 0) {
      int b = m >> 11, s = m & 2047;
      ot[((size_t)(b * 16 + c)) * 2048 + s] = acc + b3[c];
    }
  }
}

// ---- wave-parallel decay recurrence + cumsum ----
// One wave per (b,c) chain (128 blocks x 64 lanes). Lane owns a 32-step
// chunk. State (m,a): m_t = d*m_{t-1} + o_t, a_t = a_{t-1} + m_t is affine
// -> per-chunk map (p=d^32, M, S=sum d^j, A); 6-step shfl_up map-compose
// scan gives each lane its incoming (m0,a0); lane replays its chunk.
__global__ __launch_bounds__(64) void scan_k(
    const float* __restrict__ ot, float* __restrict__ out) {
  const int chain = blockIdx.x;       // b*16+c
  const int lane = threadIdx.x;
  const int b = chain >> 4, c = chain & 15;
  const float dinv = __builtin_bit_cast(float, (u32)((127 - (c + 3)) << 23));
  const float d = 1.f - dinv;         // exact dyadic

  // load 32 o-values for this lane's chunk
  float o[32];
  const float4* src = (const float4*)(ot + (size_t)chain * 2048 + lane * 32);
  #pragma unroll
  for (int i = 0; i < 8; i++) {
    float4 v = src[i];
    o[i * 4 + 0] = v.x; o[i * 4 + 1] = v.y;
    o[i * 4 + 2] = v.z; o[i * 4 + 3] = v.w;
  }

  // local pass from zero state; also accumulate exact p = d^32, S = sum d^j
  float M = 0.f, A = 0.f, P = 1.f, S = 0.f;
  #pragma unroll
  for (int i = 0; i < 32; i++) {
    M = d * M + o[i];
    A += M;
    P *= d;
    S = d * S + d;  // S_j = sum_{k=1..j} d^k
  }

  // inclusive map-composition scan across lanes
  #pragma unroll
  for (int off = 1; off < 64; off <<= 1) {
    float Pp = __shfl_up(P, off, 64);
    float Mp = __shfl_up(M, off, 64);
    float Sp = __shfl_up(S, off, 64);
    float Ap = __shfl_up(A, off, 64);
    if (lane >= off) {
      float A2 = Ap + S * Mp + A;
      float S2 = Sp + S * Pp;
      float M2 = P * Mp + M;
      float P2 = Pp * P;
      A = A2; S = S2; M = M2; P = P2;
    }
  }
  float m0 = __shfl_up(M, 1, 64);
  float a0 = __shfl_up(A, 1, 64);
  if (lane == 0) { m0 = 0.f; a0 = 0.f; }

  // replay with correct incoming state and write out[b*32768 + t*16 + c]
  float* dst = out + (size_t)b * 32768 + (size_t)(lane * 32) * 16 + c;
  float m = m0, a = a0;
  #pragma unroll
  for (int i = 0; i < 32; i++) {
    m = d * m + o[i];
    a += m;
    dst[i * 16] = a;
  }
}

extern "C" void kernel_launch(void* const* d_in, const int* in_sizes, int n_in,
                              void* d_out, int out_size, void* d_ws, size_t ws_size,
                              hipStream_t stream) {
  const float* x  = (const float*)d_in[0];
  const float* w1 = (const float*)d_in[1];
  const float* b1 = (const float*)d_in[2];
  const float* w2 = (const float*)d_in[3];
  const float* b2 = (const float*)d_in[4];
  const float* w3 = (const float*)d_in[5];
  const float* b3 = (const float*)d_in[6];
  // d_in[7] (D) intentionally unused: decay recurrence replaces the einsum.
  float* out = (float*)d_out;

  char* ws = (char*)d_ws;
  size_t off = 0;
  u16* A1  = (u16*)(ws + off); off += (size_t)16384 * 512 * 2;   // x bf16
  u16* h1  = (u16*)(ws + off); off += (size_t)16384 * 1024 * 2;  // layer1 out
  u16* h2  = (u16*)(ws + off); off += (size_t)16384 * 1024 * 2;  // layer2 out
  u16* w1t = (u16*)(ws + off); off += (size_t)1024 * 512 * 2;
  u16* w2t = (u16*)(ws + off); off += (size_t)1024 * 1024 * 2;
  u16* w3t = (u16*)(ws + off); off += (size_t)16 * 1024 * 2;
  float* ot = (float*)(ws + off); off += (size_t)128 * 2048 * 4; // [b*16+c][t]

  cast_f32_bf16_k<<<8192, 256, 0, stream>>>((const float4*)x, (uint2*)A1,
                                            16384 * 512 / 4);
  dim3 tb(32, 8);
  transpose_cast_k<<<dim3(32, 16), tb, 0, stream>>>(w1, w1t, 512, 1024);
  transpose_cast_k<<<dim3(32, 32), tb, 0, stream>>>(w2, w2t, 1024, 1024);
  transpose_cast_k<<<dim3(1, 32),  tb, 0, stream>>>(w3, w3t, 1024, 16);

  gemm_bt_k<<<512, 512, 0, stream>>>(A1, w1t, b1, h1, 16384, 1024, 512, 1);
  gemm_bt_k<<<512, 512, 0, stream>>>(h1, w2t, b2, h2, 16384, 1024, 1024, 1);
  gemm3_k<<<2048, 256, 0, stream>>>(h2, w3t, b3, ot, 16384);
  scan_k<<<128, 64, 0, stream>>>(ot, out);
}